// Round 1
// baseline (496.636 us; speedup 1.0000x reference)
//
#include <hip/hip_runtime.h>
#include <math.h>

// MHA fwd: B=8 H=16 T=1024 D=1024 dh=64. fp32 in/out, bf16 MFMA compute.
// Precision: logits sigma~1024 => QK path needs ~fp32 accuracy => split-bf16
// (hi+lo) 3-term MFMA for x@Wq, x@Wk and Q@K^T. Everything else plain bf16.

typedef unsigned short u16;
typedef __bf16  bf16x8 __attribute__((ext_vector_type(8)));
typedef unsigned short u16x8 __attribute__((ext_vector_type(8)));
typedef float f32x4 __attribute__((ext_vector_type(4)));

#define MFMA16(a,b,c) __builtin_amdgcn_mfma_f32_16x16x32_bf16((a),(b),(c),0,0,0)

static __device__ __forceinline__ u16 f2b(float f){
  unsigned u = __builtin_bit_cast(unsigned, f);
  u += 0x7fffu + ((u >> 16) & 1u);            // RNE, no NaN handling (none occur)
  return (u16)(u >> 16);
}
static __device__ __forceinline__ float b2f(u16 h){
  unsigned u = ((unsigned)h) << 16;
  return __builtin_bit_cast(float, u);
}
static __device__ __forceinline__ bf16x8 ldsfrag(const u16* p){
  return __builtin_bit_cast(bf16x8, *(const u16x8*)p);
}
// async global->LDS, 16B per lane; LDS dest = wave-uniform base + lane*16
static __device__ __forceinline__ void gld16(const void* g, void* l){
  __builtin_amdgcn_global_load_lds(
      (const __attribute__((address_space(1))) void*)g,
      (__attribute__((address_space(3))) void*)l, 16, 0, 0);
}

// ---------------- split x (fp32 -> hi/lo bf16) ----------------
__global__ __launch_bounds__(256) void split_x_kernel(
    const float* __restrict__ x, u16* __restrict__ xh, u16* __restrict__ xl, int n)
{
  int i = (blockIdx.x * 256 + threadIdx.x) * 8;
  if (i >= n) return;
  float4 v0 = *(const float4*)(x + i);
  float4 v1 = *(const float4*)(x + i + 4);
  float vv[8] = {v0.x, v0.y, v0.z, v0.w, v1.x, v1.y, v1.z, v1.w};
  u16x8 hv, lv;
#pragma unroll
  for (int j = 0; j < 8; j++){
    u16 hb = f2b(vv[j]);
    hv[j] = hb;
    lv[j] = f2b(vv[j] - b2f(hb));
  }
  *(u16x8*)(xh + i) = hv;
  *(u16x8*)(xl + i) = lv;
}

// ---------------- transpose W (fp32 KxN -> bf16 NxK, optional lo) ----------------
__global__ __launch_bounds__(256) void transpose_split_kernel(
    const float* __restrict__ W, u16* __restrict__ Th, u16* __restrict__ Tl,
    int KD, int ND)
{
  __shared__ float t[32][33];
  int n0 = blockIdx.x * 32, k0 = blockIdx.y * 32;
  int tx = threadIdx.x, ty = threadIdx.y;
#pragma unroll
  for (int i = 0; i < 4; i++){
    int k = k0 + ty + i * 8;
    t[ty + i * 8][tx] = W[(size_t)k * ND + n0 + tx];
  }
  __syncthreads();
#pragma unroll
  for (int i = 0; i < 4; i++){
    int n = n0 + ty + i * 8;
    float v = t[tx][ty + i * 8];
    u16 h = f2b(v);
    Th[(size_t)n * KD + k0 + tx] = h;
    if (Tl) Tl[(size_t)n * KD + k0 + tx] = f2b(v - b2f(h));
  }
}

// ---------------- transpose V: [b][t][h*64+d] -> [bh][d][t] ----------------
__global__ __launch_bounds__(256) void transpose_v_kernel(
    const u16* __restrict__ V, u16* __restrict__ Vt)
{
  __shared__ u16 t[32][33];
  int d0 = blockIdx.x * 32, t0 = blockIdx.y * 32, bh = blockIdx.z;
  int b = bh >> 4, h = bh & 15;
  int tx = threadIdx.x, ty = threadIdx.y;
#pragma unroll
  for (int i = 0; i < 4; i++){
    int tt = t0 + ty + i * 8;
    t[ty + i * 8][tx] = V[(size_t)(b * 1024 + tt) * 1024 + h * 64 + d0 + tx];
  }
  __syncthreads();
#pragma unroll
  for (int i = 0; i < 4; i++){
    int d = d0 + ty + i * 8;
    Vt[((size_t)bh * 64 + d) * 1024 + t0 + tx] = t[tx][ty + i * 8];
  }
}

// ---------------- plain bf16 GEMM: C[M][N] = A[M][K] * Bt[N][K]^T ----------------
template<int OUTBF16>
__global__ __launch_bounds__(256) void gemm_bt_kernel(
    const u16* __restrict__ A, const u16* __restrict__ Bt, void* __restrict__ Cv,
    int M, int N, int K)
{
  __shared__ __attribute__((aligned(16))) u16 lA[4096], lB[4096];
  const int tid = threadIdx.x, lane = tid & 63, wave = tid >> 6;
  const int quad = lane >> 4, l15 = lane & 15;
  const int row0 = blockIdx.x * 128, col0 = blockIdx.y * 128;
  const int wm = wave >> 1, wn = wave & 1;
  const int sr = lane >> 2, sc = (lane & 3) * 8;
  f32x4 acc[4][4];
#pragma unroll
  for (int mt = 0; mt < 4; mt++)
#pragma unroll
    for (int nt = 0; nt < 4; nt++) acc[mt][nt] = (f32x4)0.0f;

  for (int k0 = 0; k0 < K; k0 += 32){
#pragma unroll
    for (int i = 0; i < 2; i++){
      int c = wave * 2 + i;                         // 0..7
      gld16(A  + (size_t)(row0 + c * 16 + sr) * K + k0 + sc, &lA[c * 512]);
      gld16(Bt + (size_t)(col0 + c * 16 + sr) * K + k0 + sc, &lB[c * 512]);
    }
    __syncthreads();
    bf16x8 a[4], b[4];
#pragma unroll
    for (int t = 0; t < 4; t++){
      a[t] = ldsfrag(&lA[(wm * 64 + t * 16 + l15) * 32 + quad * 8]);
      b[t] = ldsfrag(&lB[(wn * 64 + t * 16 + l15) * 32 + quad * 8]);
    }
#pragma unroll
    for (int mt = 0; mt < 4; mt++)
#pragma unroll
      for (int nt = 0; nt < 4; nt++)
        acc[mt][nt] = MFMA16(a[mt], b[nt], acc[mt][nt]);
    __syncthreads();
  }
#pragma unroll
  for (int mt = 0; mt < 4; mt++)
#pragma unroll
    for (int nt = 0; nt < 4; nt++)
#pragma unroll
      for (int r = 0; r < 4; r++){
        int row = row0 + wm * 64 + mt * 16 + quad * 4 + r;  // C/D: row=quad*4+reg
        int col = col0 + wn * 64 + nt * 16 + l15;           //      col=lane&15
        if (OUTBF16) ((u16*)Cv)[(size_t)row * N + col] = f2b(acc[mt][nt][r]);
        else         ((float*)Cv)[(size_t)row * N + col] = acc[mt][nt][r];
      }
}

// ---------------- 3-term split GEMM for Q||K projection, hi/lo bf16 out ----------------
__global__ __launch_bounds__(256) void gemm_qk_kernel(
    const u16* __restrict__ Ah, const u16* __restrict__ Al,
    const u16* __restrict__ Bh, const u16* __restrict__ Bl,
    u16* __restrict__ Ch, u16* __restrict__ Cl, int M, int N, int K)
{
  __shared__ __attribute__((aligned(16))) u16 lAh[4096], lAl[4096], lBh[4096], lBl[4096];
  const int tid = threadIdx.x, lane = tid & 63, wave = tid >> 6;
  const int quad = lane >> 4, l15 = lane & 15;
  const int row0 = blockIdx.x * 128, col0 = blockIdx.y * 128;
  const int wm = wave >> 1, wn = wave & 1;
  const int sr = lane >> 2, sc = (lane & 3) * 8;
  f32x4 acc[4][4];
#pragma unroll
  for (int mt = 0; mt < 4; mt++)
#pragma unroll
    for (int nt = 0; nt < 4; nt++) acc[mt][nt] = (f32x4)0.0f;

  for (int k0 = 0; k0 < K; k0 += 32){
#pragma unroll
    for (int i = 0; i < 2; i++){
      int c = wave * 2 + i;
      size_t ao = (size_t)(row0 + c * 16 + sr) * K + k0 + sc;
      size_t bo = (size_t)(col0 + c * 16 + sr) * K + k0 + sc;
      gld16(Ah + ao, &lAh[c * 512]);
      gld16(Al + ao, &lAl[c * 512]);
      gld16(Bh + bo, &lBh[c * 512]);
      gld16(Bl + bo, &lBl[c * 512]);
    }
    __syncthreads();
    bf16x8 ah[4], al[4], bh[4], bl[4];
#pragma unroll
    for (int t = 0; t < 4; t++){
      int aoff = (wm * 64 + t * 16 + l15) * 32 + quad * 8;
      int boff = (wn * 64 + t * 16 + l15) * 32 + quad * 8;
      ah[t] = ldsfrag(&lAh[aoff]);  al[t] = ldsfrag(&lAl[aoff]);
      bh[t] = ldsfrag(&lBh[boff]);  bl[t] = ldsfrag(&lBl[boff]);
    }
#pragma unroll
    for (int mt = 0; mt < 4; mt++)
#pragma unroll
      for (int nt = 0; nt < 4; nt++){
        acc[mt][nt] = MFMA16(al[mt], bh[nt], acc[mt][nt]);
        acc[mt][nt] = MFMA16(ah[mt], bl[nt], acc[mt][nt]);
        acc[mt][nt] = MFMA16(ah[mt], bh[nt], acc[mt][nt]);
      }
    __syncthreads();
  }
#pragma unroll
  for (int mt = 0; mt < 4; mt++)
#pragma unroll
    for (int nt = 0; nt < 4; nt++)
#pragma unroll
      for (int r = 0; r < 4; r++){
        int row = row0 + wm * 64 + mt * 16 + quad * 4 + r;
        int col = col0 + wn * 64 + nt * 16 + l15;
        float v = acc[mt][nt][r];
        u16 h = f2b(v);
        Ch[(size_t)row * N + col] = h;
        Cl[(size_t)row * N + col] = f2b(v - b2f(h));
      }
}

// ---------------- flash attention ----------------
// grid = B*H*8 blocks; block = 256 (4 waves). Q-tile 128 rows, K-tile 128.
// QKh/QKl: [8192][2048] (cols 0..1023 = Q feats, 1024..2047 = K feats)
// Vt: [bh][64][1024].  O out: [b*1024+t][1024] bf16.
__global__ __launch_bounds__(256) void attn_kernel(
    const u16* __restrict__ QKh, const u16* __restrict__ QKl,
    const u16* __restrict__ Vt, u16* __restrict__ O)
{
  // panel layouts (32-col pitch = m97-proven): lK*: [kc2][128][32], lV: [kc4][64][32]
  __shared__ __attribute__((aligned(16))) u16 lKh[8192], lKl[8192], lV[8192];
  __shared__ __attribute__((aligned(16))) u16 lP[4][32 * 40];  // per-wave, +8 pad
  const int tid = threadIdx.x, lane = tid & 63, wave = tid >> 6;
  const int quad = lane >> 4, l15 = lane & 15;
  const int qt = blockIdx.x & 7, bh = blockIdx.x >> 3;
  const int b = bh >> 4, h = bh & 15;
  const int q0 = qt * 128;
  const int sr = lane >> 2, sc = (lane & 3) * 8;
  const float BETA = 0.18033688011112042f;   // (1/sqrt(64)) * log2(e)

  bf16x8 qh[2][2], ql[2][2];
  { // stage Q strip once through lKh/lKl, keep frags in regs
#pragma unroll
    for (int i = 0; i < 4; i++){
      int c = wave * 4 + i;                       // 0..15
      int r = (c & 7) * 16 + sr;                  // 0..127
      int col = (c >> 3) * 32 + sc;               // 0..63
      size_t g = (size_t)(b * 1024 + q0 + r) * 2048 + h * 64 + col;
      gld16(QKh + g, &lKh[c * 512]);
      gld16(QKl + g, &lKl[c * 512]);
    }
    __syncthreads();
#pragma unroll
    for (int mt = 0; mt < 2; mt++)
#pragma unroll
      for (int kc = 0; kc < 2; kc++){
        int off = kc * 4096 + (wave * 32 + mt * 16 + l15) * 32 + quad * 8;
        qh[mt][kc] = ldsfrag(&lKh[off]);
        ql[mt][kc] = ldsfrag(&lKl[off]);
      }
    __syncthreads();
  }

  float m_i[2][4], l_i[2][4];
  f32x4 o_acc[2][4];
#pragma unroll
  for (int mt = 0; mt < 2; mt++){
#pragma unroll
    for (int r = 0; r < 4; r++){ m_i[mt][r] = -3.0e38f; l_i[mt][r] = 0.0f; }
#pragma unroll
    for (int nd = 0; nd < 4; nd++) o_acc[mt][nd] = (f32x4)0.0f;
  }

  for (int kt = 0; kt < 8; kt++){
    const int k0 = kt * 128;
#pragma unroll
    for (int i = 0; i < 4; i++){
      int c = wave * 4 + i;
      int r = (c & 7) * 16 + sr;
      int col = (c >> 3) * 32 + sc;
      size_t g = (size_t)(b * 1024 + k0 + r) * 2048 + 1024 + h * 64 + col;
      gld16(QKh + g, &lKh[c * 512]);
      gld16(QKl + g, &lKl[c * 512]);
      int d = (c & 3) * 16 + sr;
      int cv = (c >> 2) * 32 + sc;
      gld16(Vt + ((size_t)bh * 64 + d) * 1024 + k0 + cv, &lV[c * 512]);
    }
    __syncthreads();

    // S = Q.K^T (3-term split for accuracy), wave owns rows wave*32..+31
    f32x4 s[2][8];
#pragma unroll
    for (int mt = 0; mt < 2; mt++)
#pragma unroll
      for (int nt = 0; nt < 8; nt++) s[mt][nt] = (f32x4)0.0f;
#pragma unroll
    for (int nt = 0; nt < 8; nt++){
      int boff = (nt * 16 + l15) * 32 + quad * 8;
      bf16x8 kh0 = ldsfrag(&lKh[boff]);
      bf16x8 kh1 = ldsfrag(&lKh[4096 + boff]);
      bf16x8 kl0 = ldsfrag(&lKl[boff]);
      bf16x8 kl1 = ldsfrag(&lKl[4096 + boff]);
#pragma unroll
      for (int mt = 0; mt < 2; mt++){
        s[mt][nt] = MFMA16(ql[mt][0], kh0, s[mt][nt]);
        s[mt][nt] = MFMA16(ql[mt][1], kh1, s[mt][nt]);
        s[mt][nt] = MFMA16(qh[mt][0], kl0, s[mt][nt]);
        s[mt][nt] = MFMA16(qh[mt][1], kl1, s[mt][nt]);
        s[mt][nt] = MFMA16(qh[mt][0], kh0, s[mt][nt]);
        s[mt][nt] = MFMA16(qh[mt][1], kh1, s[mt][nt]);
      }
    }

    // online softmax (exp2 domain, scale folded into BETA)
    float alpha[2][4];
#pragma unroll
    for (int mt = 0; mt < 2; mt++)
#pragma unroll
      for (int r = 0; r < 4; r++){
        float mx = s[mt][0][r];
#pragma unroll
        for (int nt = 1; nt < 8; nt++) mx = fmaxf(mx, s[mt][nt][r]);
        mx = fmaxf(mx, __shfl_xor(mx, 1));
        mx = fmaxf(mx, __shfl_xor(mx, 2));
        mx = fmaxf(mx, __shfl_xor(mx, 4));
        mx = fmaxf(mx, __shfl_xor(mx, 8));
        float mn = fmaxf(m_i[mt][r], mx);
        alpha[mt][r] = exp2f((m_i[mt][r] - mn) * BETA);
        m_i[mt][r] = mn;
      }
#pragma unroll
    for (int mt = 0; mt < 2; mt++)
#pragma unroll
      for (int r = 0; r < 4; r++){
        float rs = 0.0f;
#pragma unroll
        for (int nt = 0; nt < 8; nt++){
          float p = exp2f((s[mt][nt][r] - m_i[mt][r]) * BETA);
          s[mt][nt][r] = p;
          rs += p;
        }
        rs += __shfl_xor(rs, 1); rs += __shfl_xor(rs, 2);
        rs += __shfl_xor(rs, 4); rs += __shfl_xor(rs, 8);
        l_i[mt][r] = l_i[mt][r] * alpha[mt][r] + rs;
#pragma unroll
        for (int nd = 0; nd < 4; nd++) o_acc[mt][nd][r] *= alpha[mt][r];
      }

    // PV: P (C-layout) -> LDS -> A-layout, per 32-key chunk; wave-local, no barrier
#pragma unroll
    for (int kc = 0; kc < 4; kc++){
#pragma unroll
      for (int mt = 0; mt < 2; mt++)
#pragma unroll
        for (int ntl = 0; ntl < 2; ntl++){
          int nt = kc * 2 + ntl;
#pragma unroll
          for (int r = 0; r < 4; r++)
            lP[wave][(mt * 16 + quad * 4 + r) * 40 + ntl * 16 + l15] = f2b(s[mt][nt][r]);
        }
#pragma unroll
      for (int mt = 0; mt < 2; mt++){
        bf16x8 pa = ldsfrag(&lP[wave][(mt * 16 + l15) * 40 + quad * 8]);
#pragma unroll
        for (int nd = 0; nd < 4; nd++){
          bf16x8 vb = ldsfrag(&lV[kc * 2048 + (nd * 16 + l15) * 32 + quad * 8]);
          o_acc[mt][nd] = MFMA16(pa, vb, o_acc[mt][nd]);
        }
      }
    }
    __syncthreads();
  }

#pragma unroll
  for (int mt = 0; mt < 2; mt++)
#pragma unroll
    for (int r = 0; r < 4; r++){
      float inv = 1.0f / l_i[mt][r];
      int t = q0 + wave * 32 + mt * 16 + quad * 4 + r;
      size_t rowoff = (size_t)(b * 1024 + t) * 1024 + h * 64;
#pragma unroll
      for (int nd = 0; nd < 4; nd++)
        O[rowoff + nd * 16 + l15] = f2b(o_acc[mt][nd][r] * inv);
    }
}

// ---------------- launcher ----------------
extern "C" void kernel_launch(void* const* d_in, const int* in_sizes, int n_in,
                              void* d_out, int out_size, void* d_ws, size_t ws_size,
                              hipStream_t stream)
{
  const float* x  = (const float*)d_in[0];
  const float* Wq = (const float*)d_in[1];
  const float* Wk = (const float*)d_in[2];
  const float* Wv = (const float*)d_in[3];
  const float* Wp = (const float*)d_in[4];
  float* out = (float*)d_out;
  char* ws = (char*)d_ws;
  const size_t MB = 1024 * 1024;
  // workspace map (peak 124 MB, with reuse):
  u16* xh   = (u16*)(ws + 0);        // 16MB; reused as O after V-GEMM
  u16* xl   = (u16*)(ws + 16 * MB);  // 16MB; reused as V after QK-GEMM
  u16* wqkh = (u16*)(ws + 32 * MB);  // 4MB  [2048][1024]
  u16* wqkl = (u16*)(ws + 36 * MB);  // 4MB
  u16* wvt  = (u16*)(ws + 40 * MB);  // 2MB
  u16* wpt  = (u16*)(ws + 42 * MB);  // 2MB
  u16* qkh  = (u16*)(ws + 44 * MB);  // 32MB [8192][2048]
  u16* qkl  = (u16*)(ws + 76 * MB);  // 32MB
  u16* vt   = (u16*)(ws + 108 * MB); // 16MB [128][64][1024]
  u16* vbuf = xl;
  u16* obuf = xh;
  (void)in_sizes; (void)n_in; (void)out_size; (void)ws_size;

  dim3 tb(32, 8);
  split_x_kernel<<<4096, 256, 0, stream>>>(x, xh, xl, 8 * 1024 * 1024);
  transpose_split_kernel<<<dim3(32, 32), tb, 0, stream>>>(Wq, wqkh, wqkl, 1024, 1024);
  transpose_split_kernel<<<dim3(32, 32), tb, 0, stream>>>(Wk, wqkh + 1024 * 1024, wqkl + 1024 * 1024, 1024, 1024);
  transpose_split_kernel<<<dim3(32, 32), tb, 0, stream>>>(Wv, wvt, (u16*)nullptr, 1024, 1024);
  transpose_split_kernel<<<dim3(32, 32), tb, 0, stream>>>(Wp, wpt, (u16*)nullptr, 1024, 1024);
  gemm_qk_kernel<<<dim3(64, 16), 256, 0, stream>>>(xh, xl, wqkh, wqkl, qkh, qkl, 8192, 2048, 1024);
  gemm_bt_kernel<1><<<dim3(64, 8), 256, 0, stream>>>(xh, wvt, (void*)vbuf, 8192, 1024, 1024);
  transpose_v_kernel<<<dim3(2, 32, 128), tb, 0, stream>>>(vbuf, vt);
  attn_kernel<<<1024, 256, 0, stream>>>(qkh, qkl, vt, obuf);
  gemm_bt_kernel<0><<<dim3(64, 8), 256, 0, stream>>>(obuf, wpt, (void*)out, 8192, 1024, 1024);
}

// Round 2
// 489.019 us; speedup vs baseline: 1.0156x; 1.0156x over previous
//
#include <hip/hip_runtime.h>
#include <math.h>

// MHA fwd: B=8 H=16 T=1024 D=1024 dh=64. fp32 in/out, bf16 MFMA compute.
// Precision: logits sigma~1024 => QK path needs ~fp32 accuracy => split-bf16
// (hi+lo) 3-term MFMA for x@Wq, x@Wk and Q@K^T. Everything else plain bf16.
// R1: attn computes S^T = K.Q^T so softmax is in-lane and P's C-layout is
// directly the A-frag layout of mfma_16x16x16_bf16 (no LDS round-trip).

typedef unsigned short u16;
typedef unsigned int u32;
typedef __bf16  bf16x8 __attribute__((ext_vector_type(8)));
typedef unsigned short u16x8 __attribute__((ext_vector_type(8)));
typedef unsigned short u16x4 __attribute__((ext_vector_type(4)));
typedef short s16x4 __attribute__((ext_vector_type(4)));
typedef unsigned int u32x2 __attribute__((ext_vector_type(2)));
typedef float f32x4 __attribute__((ext_vector_type(4)));

#define MFMA16(a,b,c) __builtin_amdgcn_mfma_f32_16x16x32_bf16((a),(b),(c),0,0,0)
#define MFMA16K16(a,b,c) __builtin_amdgcn_mfma_f32_16x16x16bf16_1k((a),(b),(c),0,0,0)

static __device__ __forceinline__ u16 f2b(float f){
  unsigned u = __builtin_bit_cast(unsigned, f);
  u += 0x7fffu + ((u >> 16) & 1u);            // RNE, no NaN handling (none occur)
  return (u16)(u >> 16);
}
static __device__ __forceinline__ float b2f(u16 h){
  unsigned u = ((unsigned)h) << 16;
  return __builtin_bit_cast(float, u);
}
static __device__ __forceinline__ bf16x8 ldsfrag(const u16* p){
  return __builtin_bit_cast(bf16x8, *(const u16x8*)p);
}
// pack hi16(fa)<<16 | hi16(fb) in one v_perm_b32 (bf16 truncation)
static __device__ __forceinline__ u32 packhi(float fa, float fb){
  return __builtin_amdgcn_perm(__builtin_bit_cast(u32, fa),
                               __builtin_bit_cast(u32, fb), 0x07060302u);
}
// async global->LDS, 16B per lane; LDS dest = wave-uniform base + lane*16
static __device__ __forceinline__ void gld16(const void* g, void* l){
  __builtin_amdgcn_global_load_lds(
      (const __attribute__((address_space(1))) void*)g,
      (__attribute__((address_space(3))) void*)l, 16, 0, 0);
}

// ---------------- split x (fp32 -> hi/lo bf16) ----------------
__global__ __launch_bounds__(256) void split_x_kernel(
    const float* __restrict__ x, u16* __restrict__ xh, u16* __restrict__ xl, int n)
{
  int i = (blockIdx.x * 256 + threadIdx.x) * 8;
  if (i >= n) return;
  float4 v0 = *(const float4*)(x + i);
  float4 v1 = *(const float4*)(x + i + 4);
  float vv[8] = {v0.x, v0.y, v0.z, v0.w, v1.x, v1.y, v1.z, v1.w};
  u16x8 hv, lv;
#pragma unroll
  for (int j = 0; j < 8; j++){
    u16 hb = f2b(vv[j]);
    hv[j] = hb;
    lv[j] = f2b(vv[j] - b2f(hb));
  }
  *(u16x8*)(xh + i) = hv;
  *(u16x8*)(xl + i) = lv;
}

// ---------------- transpose W (fp32 KxN -> bf16 NxK, optional lo) ----------------
__global__ __launch_bounds__(256) void transpose_split_kernel(
    const float* __restrict__ W, u16* __restrict__ Th, u16* __restrict__ Tl,
    int KD, int ND)
{
  __shared__ float t[32][33];
  int n0 = blockIdx.x * 32, k0 = blockIdx.y * 32;
  int tx = threadIdx.x, ty = threadIdx.y;
#pragma unroll
  for (int i = 0; i < 4; i++){
    int k = k0 + ty + i * 8;
    t[ty + i * 8][tx] = W[(size_t)k * ND + n0 + tx];
  }
  __syncthreads();
#pragma unroll
  for (int i = 0; i < 4; i++){
    int n = n0 + ty + i * 8;
    float v = t[tx][ty + i * 8];
    u16 h = f2b(v);
    Th[(size_t)n * KD + k0 + tx] = h;
    if (Tl) Tl[(size_t)n * KD + k0 + tx] = f2b(v - b2f(h));
  }
}

// ---------------- transpose V: [b][t][h*64+d] -> [bh][d][t] ----------------
__global__ __launch_bounds__(256) void transpose_v_kernel(
    const u16* __restrict__ V, u16* __restrict__ Vt)
{
  __shared__ u16 t[32][33];
  int d0 = blockIdx.x * 32, t0 = blockIdx.y * 32, bh = blockIdx.z;
  int b = bh >> 4, h = bh & 15;
  int tx = threadIdx.x, ty = threadIdx.y;
#pragma unroll
  for (int i = 0; i < 4; i++){
    int tt = t0 + ty + i * 8;
    t[ty + i * 8][tx] = V[(size_t)(b * 1024 + tt) * 1024 + h * 64 + d0 + tx];
  }
  __syncthreads();
#pragma unroll
  for (int i = 0; i < 4; i++){
    int d = d0 + ty + i * 8;
    Vt[((size_t)bh * 64 + d) * 1024 + t0 + tx] = t[tx][ty + i * 8];
  }
}

// ---------------- plain bf16 GEMM: C[M][N] = A[M][K] * Bt[N][K]^T ----------------
template<int OUTBF16>
__global__ __launch_bounds__(256) void gemm_bt_kernel(
    const u16* __restrict__ A, const u16* __restrict__ Bt, void* __restrict__ Cv,
    int M, int N, int K)
{
  __shared__ __attribute__((aligned(16))) u16 lA[4096], lB[4096];
  const int tid = threadIdx.x, lane = tid & 63, wave = tid >> 6;
  const int quad = lane >> 4, l15 = lane & 15;
  const int row0 = blockIdx.x * 128, col0 = blockIdx.y * 128;
  const int wm = wave >> 1, wn = wave & 1;
  const int sr = lane >> 2, sc = (lane & 3) * 8;
  f32x4 acc[4][4];
#pragma unroll
  for (int mt = 0; mt < 4; mt++)
#pragma unroll
    for (int nt = 0; nt < 4; nt++) acc[mt][nt] = (f32x4)0.0f;

  for (int k0 = 0; k0 < K; k0 += 32){
#pragma unroll
    for (int i = 0; i < 2; i++){
      int c = wave * 2 + i;                         // 0..7
      gld16(A  + (size_t)(row0 + c * 16 + sr) * K + k0 + sc, &lA[c * 512]);
      gld16(Bt + (size_t)(col0 + c * 16 + sr) * K + k0 + sc, &lB[c * 512]);
    }
    __syncthreads();
    bf16x8 a[4], b[4];
#pragma unroll
    for (int t = 0; t < 4; t++){
      a[t] = ldsfrag(&lA[(wm * 64 + t * 16 + l15) * 32 + quad * 8]);
      b[t] = ldsfrag(&lB[(wn * 64 + t * 16 + l15) * 32 + quad * 8]);
    }
#pragma unroll
    for (int mt = 0; mt < 4; mt++)
#pragma unroll
      for (int nt = 0; nt < 4; nt++)
        acc[mt][nt] = MFMA16(a[mt], b[nt], acc[mt][nt]);
    __syncthreads();
  }
#pragma unroll
  for (int mt = 0; mt < 4; mt++)
#pragma unroll
    for (int nt = 0; nt < 4; nt++)
#pragma unroll
      for (int r = 0; r < 4; r++){
        int row = row0 + wm * 64 + mt * 16 + quad * 4 + r;  // C/D: row=quad*4+reg
        int col = col0 + wn * 64 + nt * 16 + l15;           //      col=lane&15
        if (OUTBF16) ((u16*)Cv)[(size_t)row * N + col] = f2b(acc[mt][nt][r]);
        else         ((float*)Cv)[(size_t)row * N + col] = acc[mt][nt][r];
      }
}

// ---------------- 3-term split GEMM for Q||K projection, hi/lo bf16 out ----------------
__global__ __launch_bounds__(256) void gemm_qk_kernel(
    const u16* __restrict__ Ah, const u16* __restrict__ Al,
    const u16* __restrict__ Bh, const u16* __restrict__ Bl,
    u16* __restrict__ Ch, u16* __restrict__ Cl, int M, int N, int K)
{
  __shared__ __attribute__((aligned(16))) u16 lAh[4096], lAl[4096], lBh[4096], lBl[4096];
  const int tid = threadIdx.x, lane = tid & 63, wave = tid >> 6;
  const int quad = lane >> 4, l15 = lane & 15;
  const int row0 = blockIdx.x * 128, col0 = blockIdx.y * 128;
  const int wm = wave >> 1, wn = wave & 1;
  const int sr = lane >> 2, sc = (lane & 3) * 8;
  f32x4 acc[4][4];
#pragma unroll
  for (int mt = 0; mt < 4; mt++)
#pragma unroll
    for (int nt = 0; nt < 4; nt++) acc[mt][nt] = (f32x4)0.0f;

  for (int k0 = 0; k0 < K; k0 += 32){
#pragma unroll
    for (int i = 0; i < 2; i++){
      int c = wave * 2 + i;
      size_t ao = (size_t)(row0 + c * 16 + sr) * K + k0 + sc;
      size_t bo = (size_t)(col0 + c * 16 + sr) * K + k0 + sc;
      gld16(Ah + ao, &lAh[c * 512]);
      gld16(Al + ao, &lAl[c * 512]);
      gld16(Bh + bo, &lBh[c * 512]);
      gld16(Bl + bo, &lBl[c * 512]);
    }
    __syncthreads();
    bf16x8 ah[4], al[4], bh[4], bl[4];
#pragma unroll
    for (int t = 0; t < 4; t++){
      int aoff = (wm * 64 + t * 16 + l15) * 32 + quad * 8;
      int boff = (wn * 64 + t * 16 + l15) * 32 + quad * 8;
      ah[t] = ldsfrag(&lAh[aoff]);  al[t] = ldsfrag(&lAl[aoff]);
      bh[t] = ldsfrag(&lBh[boff]);  bl[t] = ldsfrag(&lBl[boff]);
    }
#pragma unroll
    for (int mt = 0; mt < 4; mt++)
#pragma unroll
      for (int nt = 0; nt < 4; nt++){
        acc[mt][nt] = MFMA16(al[mt], bh[nt], acc[mt][nt]);
        acc[mt][nt] = MFMA16(ah[mt], bl[nt], acc[mt][nt]);
        acc[mt][nt] = MFMA16(ah[mt], bh[nt], acc[mt][nt]);
      }
    __syncthreads();
  }
#pragma unroll
  for (int mt = 0; mt < 4; mt++)
#pragma unroll
    for (int nt = 0; nt < 4; nt++)
#pragma unroll
      for (int r = 0; r < 4; r++){
        int row = row0 + wm * 64 + mt * 16 + quad * 4 + r;
        int col = col0 + wn * 64 + nt * 16 + l15;
        float v = acc[mt][nt][r];
        u16 h = f2b(v);
        Ch[(size_t)row * N + col] = h;
        Cl[(size_t)row * N + col] = f2b(v - b2f(h));
      }
}

// ---------------- flash attention (S^T formulation) ----------------
// grid = B*H*8 blocks; block = 256 (4 waves). Q-tile 128 rows, K-tile 128.
// QKh/QKl: [8192][2048] (cols 0..1023 = Q feats, 1024..2047 = K feats)
// Vt: [bh][64][1024].  O out: [b*1024+t][1024] bf16.
// S^T = K.Q^T: C-layout gives lane(l15)=q, (quad*4+reg)=k => softmax in-lane,
// and P is already the A-frag of mfma_16x16x16 (k=quad*4+reg) => no transpose.
__global__ __launch_bounds__(256, 3) void attn_kernel(
    const u16* __restrict__ QKh, const u16* __restrict__ QKl,
    const u16* __restrict__ Vt, u16* __restrict__ O)
{
  // panel layouts (32-col pitch): lK*: [kc2][128][32], lV: [kc4][64][32]
  __shared__ __attribute__((aligned(16))) u16 lKh[8192], lKl[8192], lV[8192];
  const int tid = threadIdx.x, lane = tid & 63, wave = tid >> 6;
  const int quad = lane >> 4, l15 = lane & 15;
  const int qt = blockIdx.x & 7, bh = blockIdx.x >> 3;
  const int b = bh >> 4, h = bh & 15;
  const int q0 = qt * 128;
  const int sr = lane >> 2, sc = (lane & 3) * 8;
  const float BETA = 0.18033688011112042f;   // (1/sqrt(64)) * log2(e)

  bf16x8 qh[2][2], ql[2][2];
  { // stage Q strip once through lKh/lKl, keep frags in regs (B-operand layout)
#pragma unroll
    for (int i = 0; i < 4; i++){
      int c = wave * 4 + i;                       // 0..15
      int r = (c & 7) * 16 + sr;                  // 0..127
      int col = (c >> 3) * 32 + sc;               // 0..63
      size_t g = (size_t)(b * 1024 + q0 + r) * 2048 + h * 64 + col;
      gld16(QKh + g, &lKh[c * 512]);
      gld16(QKl + g, &lKl[c * 512]);
    }
    __syncthreads();
#pragma unroll
    for (int mt = 0; mt < 2; mt++)
#pragma unroll
      for (int kc = 0; kc < 2; kc++){
        int off = kc * 4096 + (wave * 32 + mt * 16 + l15) * 32 + quad * 8;
        qh[mt][kc] = ldsfrag(&lKh[off]);
        ql[mt][kc] = ldsfrag(&lKl[off]);
      }
    __syncthreads();
  }

  float m_i[2] = {-3.0e38f, -3.0e38f}, l_i[2] = {0.0f, 0.0f};
  f32x4 o_acc[2][4];
#pragma unroll
  for (int mt = 0; mt < 2; mt++)
#pragma unroll
    for (int nd = 0; nd < 4; nd++) o_acc[mt][nd] = (f32x4)0.0f;

  for (int kt = 0; kt < 8; kt++){
    const int k0 = kt * 128;
#pragma unroll
    for (int i = 0; i < 4; i++){
      int c = wave * 4 + i;
      int r = (c & 7) * 16 + sr;
      int col = (c >> 3) * 32 + sc;
      size_t g = (size_t)(b * 1024 + k0 + r) * 2048 + 1024 + h * 64 + col;
      gld16(QKh + g, &lKh[c * 512]);
      gld16(QKl + g, &lKl[c * 512]);
      int d = (c & 3) * 16 + sr;
      int cv = (c >> 2) * 32 + sc;
      gld16(Vt + ((size_t)bh * 64 + d) * 1024 + k0 + cv, &lV[c * 512]);
    }
    __syncthreads();

    // S^T[k][q]: A = K rows (l15=key), B = Q rows (l15=q). 3-term split.
    f32x4 s[2][8];
#pragma unroll
    for (int qt2 = 0; qt2 < 2; qt2++)
#pragma unroll
      for (int fkt = 0; fkt < 8; fkt++) s[qt2][fkt] = (f32x4)0.0f;
#pragma unroll
    for (int fkt = 0; fkt < 8; fkt++){
      int aoff = (fkt * 16 + l15) * 32 + quad * 8;
      bf16x8 kh0 = ldsfrag(&lKh[aoff]);
      bf16x8 kh1 = ldsfrag(&lKh[4096 + aoff]);
      bf16x8 kl0 = ldsfrag(&lKl[aoff]);
      bf16x8 kl1 = ldsfrag(&lKl[4096 + aoff]);
#pragma unroll
      for (int qt2 = 0; qt2 < 2; qt2++){
        s[qt2][fkt] = MFMA16(kl0, qh[qt2][0], s[qt2][fkt]);
        s[qt2][fkt] = MFMA16(kl1, qh[qt2][1], s[qt2][fkt]);
        s[qt2][fkt] = MFMA16(kh0, ql[qt2][0], s[qt2][fkt]);
        s[qt2][fkt] = MFMA16(kh1, ql[qt2][1], s[qt2][fkt]);
        s[qt2][fkt] = MFMA16(kh0, qh[qt2][0], s[qt2][fkt]);
        s[qt2][fkt] = MFMA16(kh1, qh[qt2][1], s[qt2][fkt]);
      }
    }

    // online softmax: per lane, q = l15 (per qt2 tile); k in-lane (32 vals)
    float alpha[2];
#pragma unroll
    for (int qt2 = 0; qt2 < 2; qt2++){
      float mx = s[qt2][0][0];
#pragma unroll
      for (int fkt = 0; fkt < 8; fkt++)
#pragma unroll
        for (int r = 0; r < 4; r++) mx = fmaxf(mx, s[qt2][fkt][r]);
      mx = fmaxf(mx, __shfl_xor(mx, 16));
      mx = fmaxf(mx, __shfl_xor(mx, 32));
      float mn = fmaxf(m_i[qt2], mx);
      alpha[qt2] = __builtin_amdgcn_exp2f((m_i[qt2] - mn) * BETA);
      m_i[qt2] = mn;
      float mb = mn * BETA;
      float rs = 0.0f;
#pragma unroll
      for (int fkt = 0; fkt < 8; fkt++)
#pragma unroll
        for (int r = 0; r < 4; r++){
          float p = __builtin_amdgcn_exp2f(s[qt2][fkt][r] * BETA - mb);
          s[qt2][fkt][r] = p;
          rs += p;
        }
      rs += __shfl_xor(rs, 16);
      rs += __shfl_xor(rs, 32);
      l_i[qt2] = l_i[qt2] * alpha[qt2] + rs;
    }

    // rescale O: alpha lives at lane l15=q; O rows are q=quad*4+r -> broadcast
#pragma unroll
    for (int mt = 0; mt < 2; mt++)
#pragma unroll
      for (int r = 0; r < 4; r++){
        float ar = __shfl(alpha[mt], quad * 4 + r);
#pragma unroll
        for (int nd = 0; nd < 4; nd++) o_acc[mt][nd][r] *= ar;
      }

    // PV via 16x16x16 MFMA: P already in A-frag layout (k=quad*4+reg)
#pragma unroll
    for (int fkt = 0; fkt < 8; fkt++){
      int vbase = (fkt >> 1) * 2048 + (fkt & 1) * 16 + quad * 4;
      s16x4 vb[4];
#pragma unroll
      for (int nd = 0; nd < 4; nd++)
        vb[nd] = __builtin_bit_cast(s16x4, *(const u16x4*)&lV[vbase + (nd * 16 + l15) * 32]);
#pragma unroll
      for (int qt2 = 0; qt2 < 2; qt2++){
        u32x2 pd;
        pd[0] = packhi(s[qt2][fkt][1], s[qt2][fkt][0]);
        pd[1] = packhi(s[qt2][fkt][3], s[qt2][fkt][2]);
        s16x4 pa = __builtin_bit_cast(s16x4, pd);
#pragma unroll
        for (int nd = 0; nd < 4; nd++)
          o_acc[qt2][nd] = MFMA16K16(pa, vb[nd], o_acc[qt2][nd]);
      }
    }
    __syncthreads();
  }

  // epilogue: l_i lives at lane l15=q; broadcast to O row-layout
#pragma unroll
  for (int mt = 0; mt < 2; mt++)
#pragma unroll
    for (int r = 0; r < 4; r++){
      float lr = __shfl(l_i[mt], quad * 4 + r);
      float inv = 1.0f / lr;
      int t = q0 + wave * 32 + mt * 16 + quad * 4 + r;
      size_t rowoff = (size_t)(b * 1024 + t) * 1024 + h * 64;
#pragma unroll
      for (int nd = 0; nd < 4; nd++)
        O[rowoff + nd * 16 + l15] = f2b(o_acc[mt][nd][r] * inv);
    }
}

// ---------------- launcher ----------------
extern "C" void kernel_launch(void* const* d_in, const int* in_sizes, int n_in,
                              void* d_out, int out_size, void* d_ws, size_t ws_size,
                              hipStream_t stream)
{
  const float* x  = (const float*)d_in[0];
  const float* Wq = (const float*)d_in[1];
  const float* Wk = (const float*)d_in[2];
  const float* Wv = (const float*)d_in[3];
  const float* Wp = (const float*)d_in[4];
  float* out = (float*)d_out;
  char* ws = (char*)d_ws;
  const size_t MB = 1024 * 1024;
  // workspace map (peak 124 MB, with reuse):
  u16* xh   = (u16*)(ws + 0);        // 16MB; reused as O after V-GEMM
  u16* xl   = (u16*)(ws + 16 * MB);  // 16MB; reused as V after QK-GEMM
  u16* wqkh = (u16*)(ws + 32 * MB);  // 4MB  [2048][1024]
  u16* wqkl = (u16*)(ws + 36 * MB);  // 4MB
  u16* wvt  = (u16*)(ws + 40 * MB);  // 2MB
  u16* wpt  = (u16*)(ws + 42 * MB);  // 2MB
  u16* qkh  = (u16*)(ws + 44 * MB);  // 32MB [8192][2048]
  u16* qkl  = (u16*)(ws + 76 * MB);  // 32MB
  u16* vt   = (u16*)(ws + 108 * MB); // 16MB [128][64][1024]
  u16* vbuf = xl;
  u16* obuf = xh;
  (void)in_sizes; (void)n_in; (void)out_size; (void)ws_size;

  dim3 tb(32, 8);
  split_x_kernel<<<4096, 256, 0, stream>>>(x, xh, xl, 8 * 1024 * 1024);
  transpose_split_kernel<<<dim3(32, 32), tb, 0, stream>>>(Wq, wqkh, wqkl, 1024, 1024);
  transpose_split_kernel<<<dim3(32, 32), tb, 0, stream>>>(Wk, wqkh + 1024 * 1024, wqkl + 1024 * 1024, 1024, 1024);
  transpose_split_kernel<<<dim3(32, 32), tb, 0, stream>>>(Wv, wvt, (u16*)nullptr, 1024, 1024);
  transpose_split_kernel<<<dim3(32, 32), tb, 0, stream>>>(Wp, wpt, (u16*)nullptr, 1024, 1024);
  gemm_qk_kernel<<<dim3(64, 16), 256, 0, stream>>>(xh, xl, wqkh, wqkl, qkh, qkl, 8192, 2048, 1024);
  gemm_bt_kernel<1><<<dim3(64, 8), 256, 0, stream>>>(xh, wvt, (void*)vbuf, 8192, 1024, 1024);
  transpose_v_kernel<<<dim3(2, 32, 128), tb, 0, stream>>>(vbuf, vt);
  attn_kernel<<<1024, 256, 0, stream>>>(qkh, qkl, vt, obuf);
  gemm_bt_kernel<0><<<dim3(64, 8), 256, 0, stream>>>(obuf, wpt, (void*)out, 8192, 1024, 1024);
}

// Round 3
// 396.977 us; speedup vs baseline: 1.2510x; 1.2319x over previous
//
#include <hip/hip_runtime.h>
#include <math.h>

// MHA fwd: B=8 H=16 T=1024 D=1024 dh=64. fp32 in/out, bf16 MFMA compute.
// Split-bf16 (hi+lo) 3-term MFMA for x@Wq, x@Wk and Q@K^T (logits sigma~1024
// need ~fp32 accuracy). Everything else plain bf16.
// R1: S^T = K.Q^T formulation (softmax in-lane, P = A-frag of 16x16x16 MFMA).
// R2: Q/K/V stored FRAG-MAJOR in per-(b,h) panels by the producers =>
//     attn staging is contiguous 1KB-per-instr, LDS reads lane-linear
//     (conflict-free), and qt-major grid swizzle gives same-XCD L2 reuse
//     of K/V across the 8 q-tiles of each (b,h).

typedef unsigned short u16;
typedef unsigned int u32;
typedef __bf16  bf16x8 __attribute__((ext_vector_type(8)));
typedef unsigned short u16x8 __attribute__((ext_vector_type(8)));
typedef unsigned short u16x4 __attribute__((ext_vector_type(4)));
typedef short s16x4 __attribute__((ext_vector_type(4)));
typedef unsigned int u32x2 __attribute__((ext_vector_type(2)));
typedef float f32x4 __attribute__((ext_vector_type(4)));

#define MFMA16(a,b,c) __builtin_amdgcn_mfma_f32_16x16x32_bf16((a),(b),(c),0,0,0)
#define MFMA16K16(a,b,c) __builtin_amdgcn_mfma_f32_16x16x16bf16_1k((a),(b),(c),0,0,0)

static __device__ __forceinline__ u16 f2b(float f){
  unsigned u = __builtin_bit_cast(unsigned, f);
  u += 0x7fffu + ((u >> 16) & 1u);            // RNE
  return (u16)(u >> 16);
}
static __device__ __forceinline__ float b2f(u16 h){
  unsigned u = ((unsigned)h) << 16;
  return __builtin_bit_cast(float, u);
}
static __device__ __forceinline__ bf16x8 ldsfrag(const u16* p){
  return __builtin_bit_cast(bf16x8, *(const u16x8*)p);
}
static __device__ __forceinline__ u32 packhi(float fa, float fb){
  return __builtin_amdgcn_perm(__builtin_bit_cast(u32, fa),
                               __builtin_bit_cast(u32, fb), 0x07060302u);
}
static __device__ __forceinline__ void gld16(const void* g, void* l){
  __builtin_amdgcn_global_load_lds(
      (const __attribute__((address_space(1))) void*)g,
      (__attribute__((address_space(3))) void*)l, 16, 0, 0);
}

// Frag-major panel conventions (u16 index), bh = b*16+h, tt = t&1023, d in [0,64):
//  K (A-frag of 16x16x32):  ktile=tt>>7 fkt=(tt>>4)&7 l15=tt&15 | kc=d>>5 q=(d>>3)&3 j=d&7
//    idx = (((bh*8+ktile)*8+fkt)*2+kc)*512 + (q*16+l15)*8 + j          [16KB/ktile]
//  Q (B-frag of 16x16x32):  qtile=tt>>7 r=tt&127 wv=r>>5 mt=(r>>4)&1 l15=tt&15
//    idx = ((((bh*8+qtile)*4+wv)*2+mt)*2+kc)*512 + (q*16+l15)*8 + j    [16KB/qtile]
//  V (B-frag of 16x16x16):  ktile=tt>>7 fkt=(tt>>4)&7 q=(tt>>2)&3 j=tt&3 | nd=d>>4 l15=d&15
//    idx = ((((bh*8+ktile)*8+fkt)*4+nd)*64 + q*16+l15)*4 + j           [16KB/ktile]

// ---------------- split x (fp32 -> hi/lo bf16) ----------------
__global__ __launch_bounds__(256) void split_x_kernel(
    const float* __restrict__ x, u16* __restrict__ xh, u16* __restrict__ xl, int n)
{
  int i = (blockIdx.x * 256 + threadIdx.x) * 8;
  if (i >= n) return;
  float4 v0 = *(const float4*)(x + i);
  float4 v1 = *(const float4*)(x + i + 4);
  float vv[8] = {v0.x, v0.y, v0.z, v0.w, v1.x, v1.y, v1.z, v1.w};
  u16x8 hv, lv;
#pragma unroll
  for (int j = 0; j < 8; j++){
    u16 hb = f2b(vv[j]);
    hv[j] = hb;
    lv[j] = f2b(vv[j] - b2f(hb));
  }
  *(u16x8*)(xh + i) = hv;
  *(u16x8*)(xl + i) = lv;
}

// ---------------- transpose W (fp32 KxN -> bf16 NxK, optional lo) ----------------
__global__ __launch_bounds__(256) void transpose_split_kernel(
    const float* __restrict__ W, u16* __restrict__ Th, u16* __restrict__ Tl,
    int KD, int ND)
{
  __shared__ float t[32][33];
  int n0 = blockIdx.x * 32, k0 = blockIdx.y * 32;
  int tx = threadIdx.x, ty = threadIdx.y;
#pragma unroll
  for (int i = 0; i < 4; i++){
    int k = k0 + ty + i * 8;
    t[ty + i * 8][tx] = W[(size_t)k * ND + n0 + tx];
  }
  __syncthreads();
#pragma unroll
  for (int i = 0; i < 4; i++){
    int n = n0 + ty + i * 8;
    float v = t[tx][ty + i * 8];
    u16 h = f2b(v);
    Th[(size_t)n * KD + k0 + tx] = h;
    if (Tl) Tl[(size_t)n * KD + k0 + tx] = f2b(v - b2f(h));
  }
}

// ---------------- V -> frag-major panels ----------------
// V: [8192][1024] bf16 row-major. Each thread handles (bh, tt..tt+3, d): the
// 4 consecutive keys are j=0..3 => one contiguous u16x4 store.
__global__ __launch_bounds__(256) void vfrag_kernel(
    const u16* __restrict__ V, u16* __restrict__ Vf)
{
  int d = threadIdx.x;                       // 0..63
  int tt = (blockIdx.x * 4 + threadIdx.y) * 4;
  int bh = blockIdx.y;
  int b = bh >> 4, h = bh & 15;
  u16x4 vals;
#pragma unroll
  for (int j = 0; j < 4; j++)
    vals[j] = V[(size_t)(b * 1024 + tt + j) * 1024 + h * 64 + d];
  int ktile = tt >> 7, fkt = (tt >> 4) & 7, q = (tt >> 2) & 3;
  int nd = d >> 4, l15 = d & 15;
  size_t idx = ((((size_t)(bh * 8 + ktile) * 8 + fkt) * 4 + nd) * 64 + q * 16 + l15) * 4;
  *(u16x4*)(Vf + idx) = vals;
}

// ---------------- plain bf16 GEMM: C[M][N] = A[M][K] * Bt[N][K]^T ----------------
template<int OUTBF16>
__global__ __launch_bounds__(256) void gemm_bt_kernel(
    const u16* __restrict__ A, const u16* __restrict__ Bt, void* __restrict__ Cv,
    int M, int N, int K)
{
  __shared__ __attribute__((aligned(16))) u16 lA[4096], lB[4096];
  const int tid = threadIdx.x, lane = tid & 63, wave = tid >> 6;
  const int quad = lane >> 4, l15 = lane & 15;
  const int row0 = blockIdx.x * 128, col0 = blockIdx.y * 128;
  const int wm = wave >> 1, wn = wave & 1;
  const int sr = lane >> 2, sc = (lane & 3) * 8;
  f32x4 acc[4][4];
#pragma unroll
  for (int mt = 0; mt < 4; mt++)
#pragma unroll
    for (int nt = 0; nt < 4; nt++) acc[mt][nt] = (f32x4)0.0f;

  for (int k0 = 0; k0 < K; k0 += 32){
#pragma unroll
    for (int i = 0; i < 2; i++){
      int c = wave * 2 + i;
      gld16(A  + (size_t)(row0 + c * 16 + sr) * K + k0 + sc, &lA[c * 512]);
      gld16(Bt + (size_t)(col0 + c * 16 + sr) * K + k0 + sc, &lB[c * 512]);
    }
    __syncthreads();
    bf16x8 a[4], b[4];
#pragma unroll
    for (int t = 0; t < 4; t++){
      a[t] = ldsfrag(&lA[(wm * 64 + t * 16 + l15) * 32 + quad * 8]);
      b[t] = ldsfrag(&lB[(wn * 64 + t * 16 + l15) * 32 + quad * 8]);
    }
#pragma unroll
    for (int mt = 0; mt < 4; mt++)
#pragma unroll
      for (int nt = 0; nt < 4; nt++)
        acc[mt][nt] = MFMA16(a[mt], b[nt], acc[mt][nt]);
    __syncthreads();
  }
#pragma unroll
  for (int mt = 0; mt < 4; mt++)
#pragma unroll
    for (int nt = 0; nt < 4; nt++)
#pragma unroll
      for (int r = 0; r < 4; r++){
        int row = row0 + wm * 64 + mt * 16 + quad * 4 + r;
        int col = col0 + wn * 64 + nt * 16 + l15;
        if (OUTBF16) ((u16*)Cv)[(size_t)row * N + col] = f2b(acc[mt][nt][r]);
        else         ((float*)Cv)[(size_t)row * N + col] = acc[mt][nt][r];
      }
}

// ---------------- 3-term split GEMM for Q||K projection -> frag-major panels ----
__global__ __launch_bounds__(256) void gemm_qk_kernel(
    const u16* __restrict__ Ah, const u16* __restrict__ Al,
    const u16* __restrict__ Bh, const u16* __restrict__ Bl,
    u16* __restrict__ Qhf, u16* __restrict__ Qlf,
    u16* __restrict__ Khf, u16* __restrict__ Klf, int M, int N, int K)
{
  __shared__ __attribute__((aligned(16))) u16 lAh[4096], lAl[4096], lBh[4096], lBl[4096];
  const int tid = threadIdx.x, lane = tid & 63, wave = tid >> 6;
  const int quad = lane >> 4, l15 = lane & 15;
  const int row0 = blockIdx.x * 128, col0 = blockIdx.y * 128;
  const int wm = wave >> 1, wn = wave & 1;
  const int sr = lane >> 2, sc = (lane & 3) * 8;
  f32x4 acc[4][4];
#pragma unroll
  for (int mt = 0; mt < 4; mt++)
#pragma unroll
    for (int nt = 0; nt < 4; nt++) acc[mt][nt] = (f32x4)0.0f;

  for (int k0 = 0; k0 < K; k0 += 32){
#pragma unroll
    for (int i = 0; i < 2; i++){
      int c = wave * 2 + i;
      size_t ao = (size_t)(row0 + c * 16 + sr) * K + k0 + sc;
      size_t bo = (size_t)(col0 + c * 16 + sr) * K + k0 + sc;
      gld16(Ah + ao, &lAh[c * 512]);
      gld16(Al + ao, &lAl[c * 512]);
      gld16(Bh + bo, &lBh[c * 512]);
      gld16(Bl + bo, &lBl[c * 512]);
    }
    __syncthreads();
    bf16x8 ah[4], al[4], bh[4], bl[4];
#pragma unroll
    for (int t = 0; t < 4; t++){
      int aoff = (wm * 64 + t * 16 + l15) * 32 + quad * 8;
      int boff = (wn * 64 + t * 16 + l15) * 32 + quad * 8;
      ah[t] = ldsfrag(&lAh[aoff]);  al[t] = ldsfrag(&lAl[aoff]);
      bh[t] = ldsfrag(&lBh[boff]);  bl[t] = ldsfrag(&lBl[boff]);
    }
#pragma unroll
    for (int mt = 0; mt < 4; mt++)
#pragma unroll
      for (int nt = 0; nt < 4; nt++){
        acc[mt][nt] = MFMA16(al[mt], bh[nt], acc[mt][nt]);
        acc[mt][nt] = MFMA16(ah[mt], bl[nt], acc[mt][nt]);
        acc[mt][nt] = MFMA16(ah[mt], bh[nt], acc[mt][nt]);
      }
    __syncthreads();
  }
  // epilogue: scatter into frag-major panels (region is L2-resident; the block
  // fully covers 2 bh-panels of one tile, so writeback is dense)
  const bool isQ = (col0 < 1024);
#pragma unroll
  for (int mt = 0; mt < 4; mt++)
#pragma unroll
    for (int nt = 0; nt < 4; nt++)
#pragma unroll
      for (int r = 0; r < 4; r++){
        int row = row0 + wm * 64 + mt * 16 + quad * 4 + r;
        int col = col0 + wn * 64 + nt * 16 + l15;
        int bb = row >> 10, tt = row & 1023;
        int hh = (col >> 6) & 15, d = col & 63;
        int bhI = bb * 16 + hh;
        int kc = d >> 5, qF = (d >> 3) & 3, j = d & 7;
        float v = acc[mt][nt][r];
        u16 hi = f2b(v);
        u16 lo = f2b(v - b2f(hi));
        if (isQ){
          int qtile = tt >> 7, rr = tt & 127;
          int wv = rr >> 5, mtF = (rr >> 4) & 1, l15F = tt & 15;
          size_t idx = ((((size_t)(bhI * 8 + qtile) * 4 + wv) * 2 + mtF) * 2 + kc) * 512
                       + (qF * 16 + l15F) * 8 + j;
          Qhf[idx] = hi; Qlf[idx] = lo;
        } else {
          int ktile = tt >> 7, fkt = (tt >> 4) & 7, l15F = tt & 15;
          size_t idx = (((size_t)(bhI * 8 + ktile) * 8 + fkt) * 2 + kc) * 512
                       + (qF * 16 + l15F) * 8 + j;
          Khf[idx] = hi; Klf[idx] = lo;
        }
      }
}

// ---------------- flash attention (S^T formulation, frag-major inputs) --------
// grid = 1024; swizzle: qt = bid>>7, bh = bid&127 => same-bh blocks are 128
// apart => same XCD => K/V panels hit that XCD's L2 (8x reuse).
__global__ __launch_bounds__(256, 3) void attn_kernel(
    const u16* __restrict__ Qhf, const u16* __restrict__ Qlf,
    const u16* __restrict__ Khf, const u16* __restrict__ Klf,
    const u16* __restrict__ Vf, u16* __restrict__ O)
{
  __shared__ __attribute__((aligned(16))) u16 lKh[8192], lKl[8192], lV[8192];
  const int tid = threadIdx.x, lane = tid & 63, wave = tid >> 6;
  const int quad = lane >> 4, l15 = lane & 15;
  const int qt = blockIdx.x >> 7, bh = blockIdx.x & 127;
  const int b = bh >> 4, h = bh & 15;
  const int q0 = qt * 128;
  const float BETA = 0.18033688011112042f;   // (1/sqrt(64)) * log2(e)

  bf16x8 qh[2][2], ql[2][2];
  { // stage Q (frag-major, contiguous), keep B-frags in regs
    size_t qbase = (size_t)(bh * 8 + qt) * 8192 + wave * 2048 + lane * 8;
#pragma unroll
    for (int i = 0; i < 4; i++){
      gld16(Qhf + qbase + i * 512, &lKh[wave * 2048 + i * 512]);
      gld16(Qlf + qbase + i * 512, &lKl[wave * 2048 + i * 512]);
    }
    __syncthreads();
#pragma unroll
    for (int mt = 0; mt < 2; mt++)
#pragma unroll
      for (int kc = 0; kc < 2; kc++){
        int off = wave * 2048 + (mt * 2 + kc) * 512 + lane * 8;
        qh[mt][kc] = ldsfrag(&lKh[off]);
        ql[mt][kc] = ldsfrag(&lKl[off]);
      }
    __syncthreads();
  }

  float m_i[2] = {-3.0e38f, -3.0e38f}, l_i[2] = {0.0f, 0.0f};
  f32x4 o_acc[2][4];
#pragma unroll
  for (int mt = 0; mt < 2; mt++)
#pragma unroll
    for (int nd = 0; nd < 4; nd++) o_acc[mt][nd] = (f32x4)0.0f;

  for (int kt = 0; kt < 8; kt++){
    size_t kbase = (size_t)(bh * 8 + kt) * 8192 + wave * 2048 + lane * 8;
#pragma unroll
    for (int i = 0; i < 4; i++){
      gld16(Khf + kbase + i * 512, &lKh[wave * 2048 + i * 512]);
      gld16(Klf + kbase + i * 512, &lKl[wave * 2048 + i * 512]);
      gld16(Vf  + kbase + i * 512, &lV [wave * 2048 + i * 512]);
    }
    __syncthreads();

    // S^T = K.Q^T (A = K frags, B = Q frags), 3-term split
    f32x4 s[2][8];
#pragma unroll
    for (int qt2 = 0; qt2 < 2; qt2++)
#pragma unroll
      for (int fkt = 0; fkt < 8; fkt++) s[qt2][fkt] = (f32x4)0.0f;
#pragma unroll
    for (int fkt = 0; fkt < 8; fkt++){
      int aoff = fkt * 1024 + lane * 8;      // [fkt][kc][lane][8], lane-linear
      bf16x8 kh0 = ldsfrag(&lKh[aoff]);
      bf16x8 kh1 = ldsfrag(&lKh[aoff + 512]);
      bf16x8 kl0 = ldsfrag(&lKl[aoff]);
      bf16x8 kl1 = ldsfrag(&lKl[aoff + 512]);
#pragma unroll
      for (int qt2 = 0; qt2 < 2; qt2++){
        s[qt2][fkt] = MFMA16(kl0, qh[qt2][0], s[qt2][fkt]);
        s[qt2][fkt] = MFMA16(kl1, qh[qt2][1], s[qt2][fkt]);
        s[qt2][fkt] = MFMA16(kh0, ql[qt2][0], s[qt2][fkt]);
        s[qt2][fkt] = MFMA16(kh1, ql[qt2][1], s[qt2][fkt]);
        s[qt2][fkt] = MFMA16(kh0, qh[qt2][0], s[qt2][fkt]);
        s[qt2][fkt] = MFMA16(kh1, qh[qt2][1], s[qt2][fkt]);
      }
    }

    // online softmax: lane l15 = q; 32 k-values in-lane, 2 shuffles finish
    float alpha[2];
#pragma unroll
    for (int qt2 = 0; qt2 < 2; qt2++){
      float mx = s[qt2][0][0];
#pragma unroll
      for (int fkt = 0; fkt < 8; fkt++)
#pragma unroll
        for (int r = 0; r < 4; r++) mx = fmaxf(mx, s[qt2][fkt][r]);
      mx = fmaxf(mx, __shfl_xor(mx, 16));
      mx = fmaxf(mx, __shfl_xor(mx, 32));
      float mn = fmaxf(m_i[qt2], mx);
      alpha[qt2] = __builtin_amdgcn_exp2f((m_i[qt2] - mn) * BETA);
      m_i[qt2] = mn;
      float mb = mn * BETA;
      float rs = 0.0f;
#pragma unroll
      for (int fkt = 0; fkt < 8; fkt++)
#pragma unroll
        for (int r = 0; r < 4; r++){
          float p = __builtin_amdgcn_exp2f(s[qt2][fkt][r] * BETA - mb);
          s[qt2][fkt][r] = p;
          rs += p;
        }
      rs += __shfl_xor(rs, 16);
      rs += __shfl_xor(rs, 32);
      l_i[qt2] = l_i[qt2] * alpha[qt2] + rs;
    }

    // rescale O (alpha at lane l15=q -> broadcast to O row layout)
#pragma unroll
    for (int mt = 0; mt < 2; mt++)
#pragma unroll
      for (int r = 0; r < 4; r++){
        float ar = __shfl(alpha[mt], quad * 4 + r);
#pragma unroll
        for (int nd = 0; nd < 4; nd++) o_acc[mt][nd][r] *= ar;
      }

    // PV via 16x16x16 MFMA; P already in A-frag layout; V frags lane-linear b64
#pragma unroll
    for (int fkt = 0; fkt < 8; fkt++){
      s16x4 vb[4];
#pragma unroll
      for (int nd = 0; nd < 4; nd++)
        vb[nd] = __builtin_bit_cast(s16x4,
                   *(const u16x4*)&lV[(fkt * 4 + nd) * 256 + lane * 4]);
#pragma unroll
      for (int qt2 = 0; qt2 < 2; qt2++){
        u32x2 pd;
        pd[0] = packhi(s[qt2][fkt][1], s[qt2][fkt][0]);
        pd[1] = packhi(s[qt2][fkt][3], s[qt2][fkt][2]);
        s16x4 pa = __builtin_bit_cast(s16x4, pd);
#pragma unroll
        for (int nd = 0; nd < 4; nd++)
          o_acc[qt2][nd] = MFMA16K16(pa, vb[nd], o_acc[qt2][nd]);
      }
    }
    __syncthreads();
  }

#pragma unroll
  for (int mt = 0; mt < 2; mt++)
#pragma unroll
    for (int r = 0; r < 4; r++){
      float lr = __shfl(l_i[mt], quad * 4 + r);
      float inv = 1.0f / lr;
      int t = q0 + wave * 32 + mt * 16 + quad * 4 + r;
      size_t rowoff = (size_t)(b * 1024 + t) * 1024 + h * 64;
#pragma unroll
      for (int nd = 0; nd < 4; nd++)
        O[rowoff + nd * 16 + l15] = f2b(o_acc[mt][nd][r] * inv);
    }
}

// ---------------- launcher ----------------
extern "C" void kernel_launch(void* const* d_in, const int* in_sizes, int n_in,
                              void* d_out, int out_size, void* d_ws, size_t ws_size,
                              hipStream_t stream)
{
  const float* x  = (const float*)d_in[0];
  const float* Wq = (const float*)d_in[1];
  const float* Wk = (const float*)d_in[2];
  const float* Wv = (const float*)d_in[3];
  const float* Wp = (const float*)d_in[4];
  float* out = (float*)d_out;
  char* ws = (char*)d_ws;
  const size_t MB = 1024 * 1024;
  // workspace map (peak 124 MB):
  u16* xh   = (u16*)(ws + 0);        // 16MB; reused as O after V-GEMM
  u16* xl   = (u16*)(ws + 16 * MB);  // 16MB; reused as V after QK-GEMM
  u16* wqkh = (u16*)(ws + 32 * MB);  // 4MB  [2048][1024]
  u16* wqkl = (u16*)(ws + 36 * MB);  // 4MB
  u16* wvt  = (u16*)(ws + 40 * MB);  // 2MB
  u16* wpt  = (u16*)(ws + 42 * MB);  // 2MB
  u16* Qhf  = (u16*)(ws + 44 * MB);  // 16MB frag-major Q hi
  u16* Qlf  = (u16*)(ws + 60 * MB);  // 16MB frag-major Q lo
  u16* Khf  = (u16*)(ws + 76 * MB);  // 16MB frag-major K hi
  u16* Klf  = (u16*)(ws + 92 * MB);  // 16MB frag-major K lo
  u16* Vf   = (u16*)(ws + 108 * MB); // 16MB frag-major V
  u16* vbuf = xl;
  u16* obuf = xh;
  (void)in_sizes; (void)n_in; (void)out_size; (void)ws_size;

  dim3 tb(32, 8);
  split_x_kernel<<<4096, 256, 0, stream>>>(x, xh, xl, 8 * 1024 * 1024);
  transpose_split_kernel<<<dim3(32, 32), tb, 0, stream>>>(Wq, wqkh, wqkl, 1024, 1024);
  transpose_split_kernel<<<dim3(32, 32), tb, 0, stream>>>(Wk, wqkh + 1024 * 1024, wqkl + 1024 * 1024, 1024, 1024);
  transpose_split_kernel<<<dim3(32, 32), tb, 0, stream>>>(Wv, wvt, (u16*)nullptr, 1024, 1024);
  transpose_split_kernel<<<dim3(32, 32), tb, 0, stream>>>(Wp, wpt, (u16*)nullptr, 1024, 1024);
  gemm_qk_kernel<<<dim3(64, 16), 256, 0, stream>>>(xh, xl, wqkh, wqkl,
                                                   Qhf, Qlf, Khf, Klf, 8192, 2048, 1024);
  gemm_bt_kernel<1><<<dim3(64, 8), 256, 0, stream>>>(xh, wvt, (void*)vbuf, 8192, 1024, 1024);
  vfrag_kernel<<<dim3(64, 128), dim3(64, 4), 0, stream>>>(vbuf, Vf);
  attn_kernel<<<1024, 256, 0, stream>>>(Qhf, Qlf, Khf, Klf, Vf, obuf);
  gemm_bt_kernel<0><<<dim3(64, 8), 256, 0, stream>>>(obuf, wpt, (void*)out, 8192, 1024, 1024);
}